// Round 6
// baseline (1304.574 us; speedup 1.0000x reference)
//
#include <hip/hip_runtime.h>
#include <math.h>

// Problem constants
#define NB   32
#define NP   128
#define NM   4096        // NB*NP matrices per type
#define NMAT3 12288      // 3*NM (Q,K,V)

// ---------------------------------------------------------------------------
// K1: bimap — Q/K/V[b,p] = W * x[b,p] * W^T   (x: 64x64 SPD, W: 32x64)
// ---------------------------------------------------------------------------
__global__ __launch_bounds__(256) void bimap_kernel(
    const float* __restrict__ x, const float* __restrict__ Wq,
    const float* __restrict__ Wk, const float* __restrict__ Wv,
    float* __restrict__ qkv)
{
    __shared__ __align__(16) float S[64 * 64];
    __shared__ float Wl[32 * 65];
    __shared__ float T[32 * 65];
    const int tid = threadIdx.x;
    const int bp  = blockIdx.x;
    const float* xs = x + (size_t)bp * 4096;
#pragma unroll
    for (int k = 0; k < 4; ++k) {
        int idx = tid * 4 + k * 1024;
        *(float4*)&S[idx] = *(const float4*)&xs[idx];
    }
    const int o32 = tid & 31;
    const int grp = tid >> 5;
#pragma unroll 1
    for (int w = 0; w < 3; ++w) {
        const float* Wsrc = (w == 0) ? Wq : ((w == 1) ? Wk : Wv);
        __syncthreads();
#pragma unroll
        for (int k = 0; k < 8; ++k) {
            int f = tid + k * 256;
            Wl[(f >> 6) * 65 + (f & 63)] = Wsrc[f];
        }
        __syncthreads();
        {
            float acc[8];
#pragma unroll
            for (int jj = 0; jj < 8; ++jj) acc[jj] = 0.f;
            const int j0 = grp * 8;
#pragma unroll 4
            for (int i = 0; i < 64; ++i) {
                float wv = Wl[o32 * 65 + i];
                const float4 s0 = *(const float4*)&S[i * 64 + j0];
                const float4 s1 = *(const float4*)&S[i * 64 + j0 + 4];
                acc[0] = fmaf(wv, s0.x, acc[0]);
                acc[1] = fmaf(wv, s0.y, acc[1]);
                acc[2] = fmaf(wv, s0.z, acc[2]);
                acc[3] = fmaf(wv, s0.w, acc[3]);
                acc[4] = fmaf(wv, s1.x, acc[4]);
                acc[5] = fmaf(wv, s1.y, acc[5]);
                acc[6] = fmaf(wv, s1.z, acc[6]);
                acc[7] = fmaf(wv, s1.w, acc[7]);
            }
#pragma unroll
            for (int jj = 0; jj < 8; ++jj) T[o32 * 65 + j0 + jj] = acc[jj];
        }
        __syncthreads();
        {
            float oacc[4] = {0.f, 0.f, 0.f, 0.f};
            const int kcol = tid & 31;
            const int ob   = grp * 4;
#pragma unroll 4
            for (int j = 0; j < 64; ++j) {
                float wv = Wl[kcol * 65 + j];
#pragma unroll
                for (int cc = 0; cc < 4; ++cc)
                    oacc[cc] = fmaf(T[(ob + cc) * 65 + j], wv, oacc[cc]);
            }
            float* dst = qkv + ((size_t)w * NM + bp) * 1024;
#pragma unroll
            for (int cc = 0; cc < 4; ++cc)
                dst[(ob + cc) * 32 + kcol] = oacc[cc];
        }
    }
}

// ---------------------------------------------------------------------------
// K2/K5: batched symmetric eig-function, one-sided Jacobi, lane-per-pair
// systolic ordering (R5 structure) + TWO INDEPENDENT MATRICES PER LANE.
//
// R5 analysis: VALUBusy 93% is gfx94x-formula-inflated ~2x (CDNA4 SIMD-32
// issues wave64 in 2 cyc, not 4) -> real VALU occupancy ~46%; kernel is
// LATENCY-bound (1.5-3 waves/SIMD, serial dot->params->update->DPP chain).
// Fix: 2 independent pair-streams per lane (matrices m1,m2); their chains
// interleave, doubling ILP. 8 matrices/wave, 1536 blocks (6/CU even).
// Rotation params use HW approx rcp/rsq/sqrt (1-ulp; angles self-correct).
//
// Live set: a1,b1,a2,b2 = 128 + ~15 scalars; __launch_bounds__(64,2)
// gives a 256-VGPR budget so the allocator has no reason to spill.
// ---------------------------------------------------------------------------
__device__ __forceinline__ float ror1(float x) {   // dest i <- src (i-1)&15
    return __int_as_float(__builtin_amdgcn_mov_dpp(
        __float_as_int(x), 0x121, 0xf, 0xf, true));
}
__device__ __forceinline__ float ror15(float x) {  // dest i <- src (i+1)&15
    return __int_as_float(__builtin_amdgcn_mov_dpp(
        __float_as_int(x), 0x12F, 0xf, 0xf, true));
}

__device__ __forceinline__ float dot2(const float (&x)[32], const float (&y)[32]) {
    float g0 = 0.f, g1 = 0.f, g2 = 0.f, g3 = 0.f;
#pragma unroll
    for (int i = 0; i < 32; i += 4) {
        g0 = fmaf(x[i], y[i], g0);
        g1 = fmaf(x[i + 1], y[i + 1], g1);
        g2 = fmaf(x[i + 2], y[i + 2], g2);
        g3 = fmaf(x[i + 3], y[i + 3], g3);
    }
    return (g0 + g1) + (g2 + g3);
}

__device__ __forceinline__ void jupdate(float (&a)[32], float (&b)[32],
                                        float& alA, float& alB,
                                        float gm, bool doRot) {
    const float zeta = (alB - alA) * __builtin_amdgcn_rcpf(2.0f * gm);
    float tt = copysignf(__builtin_amdgcn_rcpf(
        fabsf(zeta) + __builtin_amdgcn_sqrtf(fmaf(zeta, zeta, 1.0f))), zeta);
    float cc = __builtin_amdgcn_rsqf(fmaf(tt, tt, 1.0f));
    float sn = cc * tt;
    if (!doRot) { cc = 1.0f; sn = 0.0f; }   // NaN-safe when gm==0
#pragma unroll
    for (int i = 0; i < 32; ++i) {
        const float ao = a[i], bo = b[i];
        a[i] = fmaf(cc, ao, -sn * bo);
        b[i] = fmaf(cc, bo,  sn * ao);
    }
    const float c2 = cc * cc, s2 = sn * sn, cs2 = 2.0f * cc * sn * gm;
    const float nA = fmaf(c2, alA, fmaf(s2, alB, -cs2));
    const float nB = fmaf(s2, alA, fmaf(c2, alB,  cs2));
    alA = nA; alB = nB;
}

__device__ __forceinline__ void migrate(float (&a)[32], float (&b)[32],
                                        float& alA, float& alB,
                                        bool l14, bool l15) {
    {
        const float alAg = ror1(alA), alBg = ror15(alB);
        const float alAo = alA;
        alA = l15 ? alBg : alAg;
        alB = l15 ? alB : (l14 ? alAo : alBg);
    }
#pragma unroll
    for (int i = 0; i < 32; ++i) {
        const float t0 = a[i];
        const float ag = ror1(t0);
        const float bg = ror15(b[i]);
        a[i] = l15 ? bg : ag;
        b[i] = l15 ? b[i] : (l14 ? t0 : bg);
    }
}

template <int MODE>
__global__ __launch_bounds__(64, 2) void eig_fn_kernel(
    const float* in, float* out, float* __restrict__ ssq, float shift)
{
    __shared__ __align__(16) float Uld[2][32 * 36];
    __shared__ __align__(16) float fld[2][32];
    const int tid  = threadIdx.x;
    const int idx  = tid & 15;           // pair index within matrix
    const int grp  = tid >> 4;           // group (0..3) -> 2 matrices each
    const bool l14 = (idx == 14), l15 = (idx == 15);
    const int cA = idx * 2, cB = idx * 2 + 1;
    const size_t m1 = (size_t)blockIdx.x * 8 + grp * 2;     // stream-1 matrix
    const size_t m2 = m1 + 1;                                // stream-2 matrix

    const float* src1 = in + m1 * 1024;
    const float* src2 = in + m2 * 1024;
    float a1[32], b1[32], a2[32], b2[32];
#pragma unroll
    for (int i = 0; i < 32; ++i) {
        float v1a = src1[i * 32 + cA], v1b = src1[i * 32 + cB];
        float v2a = src2[i * 32 + cA], v2b = src2[i * 32 + cB];
        if (MODE == 1) {
            v1a += (i == cA) ? shift : 0.0f;
            v1b += (i == cB) ? shift : 0.0f;
            v2a += (i == cA) ? shift : 0.0f;
            v2b += (i == cB) ? shift : 0.0f;
        }
        a1[i] = v1a; b1[i] = v1b; a2[i] = v2a; b2[i] = v2b;
    }

    // ---- Jacobi sweeps: 31 rounds/sweep, two independent streams ----
    for (int sweep = 0; sweep < 10; ++sweep) {
        float al1A = dot2(a1, a1), al1B = dot2(b1, b1);
        float al2A = dot2(a2, a2), al2B = dot2(b2, b2);
        bool anyrot = false;
        for (int r = 0; r < 31; ++r) {
            const float gm1 = dot2(a1, b1);
            const float gm2 = dot2(a2, b2);
            const bool d1 = gm1 * gm1 > 1e-10f * (al1A * al1B);
            const bool d2 = gm2 * gm2 > 1e-10f * (al2A * al2B);
            anyrot |= (d1 | d2);
            if (__any((int)(d1 | d2))) {
                jupdate(a1, b1, al1A, al1B, gm1, d1);
                jupdate(a2, b2, al2A, al2B, gm2, d2);
            }
            migrate(a1, b1, al1A, al1B, l14, l15);
            migrate(a2, b2, al2A, al2B, l14, l15);
        }
        if (!__any((int)anyrot)) break;
    }

    // ---- finals ----
    const float s2A1 = dot2(a1, a1), s2B1 = dot2(b1, b1);
    const float s2A2 = dot2(a2, a2), s2B2 = dot2(b2, b2);
    const float iA1 = __builtin_amdgcn_rsqf(fmaxf(s2A1, 1e-30f));
    const float iB1 = __builtin_amdgcn_rsqf(fmaxf(s2B1, 1e-30f));
    const float iA2 = __builtin_amdgcn_rsqf(fmaxf(s2A2, 1e-30f));
    const float iB2 = __builtin_amdgcn_rsqf(fmaxf(s2B2, 1e-30f));
    float fA1, fB1, fA2, fB2;
    if (MODE == 0) {
        fA1 = 0.5f * logf(fmaxf(s2A1, 1e-38f));
        fB1 = 0.5f * logf(fmaxf(s2B1, 1e-38f));
        fA2 = 0.5f * logf(fmaxf(s2A2, 1e-38f));
        fB2 = 0.5f * logf(fmaxf(s2B2, 1e-38f));
    } else {
        fA1 = expf(__builtin_amdgcn_sqrtf(s2A1) - shift);
        fB1 = expf(__builtin_amdgcn_sqrtf(s2B1) - shift);
        fA2 = expf(__builtin_amdgcn_sqrtf(s2A2) - shift);
        fB2 = expf(__builtin_amdgcn_sqrtf(s2B2) - shift);
    }

    if (MODE == 0) {
        // ||log M||_F^2 = sum_c f_c^2 (U orthogonal to ~1e-5)
        float sq1 = fA1 * fA1 + fB1 * fB1;
        float sq2 = fA2 * fA2 + fB2 * fB2;
#pragma unroll
        for (int off = 1; off < 16; off <<= 1) {
            sq1 += __shfl_xor(sq1, off);
            sq2 += __shfl_xor(sq2, off);
        }
        if (idx == 0) { ssq[m1] = sq1; ssq[m2] = sq2; }
    }

    // ---- reconstruction: out = U f(S) U^T, 4 passes of 2 matrices ----
    const int l5 = tid >> 5;   // matrix within pass
    const int c  = tid & 31;   // output column
#pragma unroll 1
    for (int pass = 0; pass < 4; ++pass) {
        __syncthreads();   // Uld reuse between passes (1-wave block: cheap)
        if (grp == pass) {
#pragma unroll
            for (int i = 0; i < 32; ++i) {
                Uld[0][i * 36 + cA] = a1[i] * iA1;
                Uld[0][i * 36 + cB] = b1[i] * iB1;
                Uld[1][i * 36 + cA] = a2[i] * iA2;
                Uld[1][i * 36 + cB] = b2[i] * iB2;
            }
            fld[0][cA] = fA1; fld[0][cB] = fB1;
            fld[1][cA] = fA2; fld[1][cB] = fB2;
        }
        __syncthreads();
        const size_t mloc = (size_t)blockIdx.x * 8 + pass * 2 + l5;
        float rr[32];   // rr[m] = f[m] * U[c][m]
        {
            const float4* urow = (const float4*)&Uld[l5][c * 36];
            const float4* frow = (const float4*)&fld[l5][0];
#pragma unroll
            for (int m4 = 0; m4 < 8; ++m4) {
                float4 u4 = urow[m4];
                float4 f4 = frow[m4];
                rr[m4 * 4 + 0] = u4.x * f4.x;
                rr[m4 * 4 + 1] = u4.y * f4.y;
                rr[m4 * 4 + 2] = u4.z * f4.z;
                rr[m4 * 4 + 3] = u4.w * f4.w;
            }
        }
        float* dst = out + mloc * 1024;
#pragma unroll
        for (int i = 0; i < 32; ++i) {
            float acc = 0.f;
            const float4* urow = (const float4*)&Uld[l5][i * 36];  // broadcast
#pragma unroll
            for (int m4 = 0; m4 < 8; ++m4) {
                float4 u4 = urow[m4];
                acc = fmaf(u4.x, rr[m4 * 4 + 0], acc);
                acc = fmaf(u4.y, rr[m4 * 4 + 1], acc);
                acc = fmaf(u4.z, rr[m4 * 4 + 2], acc);
                acc = fmaf(u4.w, rr[m4 * 4 + 3], acc);
            }
            dst[i * 32 + c] = acc;    // coalesced
        }
    }
}

// ---------------------------------------------------------------------------
// K3a: weights[b,q,k] = 1/(1+log1p(max(qq+kk-2*<LQ_q,LK_k>_F, 0)))
// ---------------------------------------------------------------------------
__global__ __launch_bounds__(256) void qk_weights_kernel(
    const float* __restrict__ L, const float* __restrict__ ssq,
    float* __restrict__ wbuf)
{
    __shared__ float Aq[32 * 37];
    __shared__ float Bk[32 * 37];
    const int b  = blockIdx.z;
    const int q0 = blockIdx.y * 32;
    const int k0 = blockIdx.x * 32;
    const int tid = threadIdx.x;
    const int tx = tid & 15, ty = tid >> 4;
    const float* LQ = L + ((size_t)b * 128 + q0) * 1024;
    const float* LK = L + (size_t)NM * 1024 + ((size_t)b * 128 + k0) * 1024;
    const int lrow = tid >> 3;
    const int lm4  = (tid & 7) * 4;
    float acc00 = 0, acc01 = 0, acc10 = 0, acc11 = 0;
    for (int m0 = 0; m0 < 1024; m0 += 32) {
        __syncthreads();
        float4 va = *(const float4*)&LQ[(size_t)lrow * 1024 + m0 + lm4];
        float4 vb = *(const float4*)&LK[(size_t)lrow * 1024 + m0 + lm4];
        Aq[lrow * 37 + lm4 + 0] = va.x; Aq[lrow * 37 + lm4 + 1] = va.y;
        Aq[lrow * 37 + lm4 + 2] = va.z; Aq[lrow * 37 + lm4 + 3] = va.w;
        Bk[lrow * 37 + lm4 + 0] = vb.x; Bk[lrow * 37 + lm4 + 1] = vb.y;
        Bk[lrow * 37 + lm4 + 2] = vb.z; Bk[lrow * 37 + lm4 + 3] = vb.w;
        __syncthreads();
#pragma unroll
        for (int mm = 0; mm < 32; ++mm) {
            float a0 = Aq[(ty * 2 + 0) * 37 + mm];
            float a1 = Aq[(ty * 2 + 1) * 37 + mm];
            float b0 = Bk[(tx * 2 + 0) * 37 + mm];
            float b1 = Bk[(tx * 2 + 1) * 37 + mm];
            acc00 = fmaf(a0, b0, acc00); acc01 = fmaf(a0, b1, acc01);
            acc10 = fmaf(a1, b0, acc10); acc11 = fmaf(a1, b1, acc11);
        }
    }
    const float* qqp = ssq + (size_t)b * 128 + q0;
    const float* kkp = ssq + NM + (size_t)b * 128 + k0;
    const int q = ty * 2, k = tx * 2;
    float* wrow0 = wbuf + ((size_t)b * 128 + q0 + q) * 128 + k0 + k;
    float* wrow1 = wrow0 + 128;
    float e;
    e = fmaxf(qqp[q] + kkp[k] - 2.0f * acc00, 0.0f);
    wrow0[0] = 1.0f / (1.0f + log1pf(e));
    e = fmaxf(qqp[q] + kkp[k + 1] - 2.0f * acc01, 0.0f);
    wrow0[1] = 1.0f / (1.0f + log1pf(e));
    e = fmaxf(qqp[q + 1] + kkp[k] - 2.0f * acc10, 0.0f);
    wrow1[0] = 1.0f / (1.0f + log1pf(e));
    e = fmaxf(qqp[q + 1] + kkp[k + 1] - 2.0f * acc11, 0.0f);
    wrow1[1] = 1.0f / (1.0f + log1pf(e));
}

// ---------------------------------------------------------------------------
// K3b: in-place softmax over the QUERY axis (column-wise on [q][k])
// ---------------------------------------------------------------------------
__global__ __launch_bounds__(256) void softmax_kernel(float* __restrict__ wbuf)
{
    __shared__ float crcp[128];
    const int t = threadIdx.x;
    float* wb = wbuf + (size_t)blockIdx.x * 16384;
    if (t < 128) {
        float ssum = 0.f;
        for (int q = 0; q < 128; ++q) ssum += expf(wb[q * 128 + t]);
        crcp[t] = 1.0f / ssum;
    }
    __syncthreads();
    for (int i = t; i < 16384; i += 256)
        wb[i] = expf(wb[i]) * crcp[i & 127];
}

// ---------------------------------------------------------------------------
// K4: mean_log[b,i,:] = sum_j soft[b,j,i] * LV[b,j,:]
// ---------------------------------------------------------------------------
__global__ __launch_bounds__(256) void meanlog_kernel(
    const float* __restrict__ soft, const float* __restrict__ LV,
    float* __restrict__ ML)
{
    __shared__ float Wt[32 * 129];
    __shared__ __align__(16) float Bl[32 * 260];
    const int b  = blockIdx.z;
    const int i0 = blockIdx.y * 32;
    const int c0 = blockIdx.x * 256;
    const int t  = threadIdx.x;
    const float* sp = soft + (size_t)b * 16384;
#pragma unroll
    for (int jb = 0; jb < 4; ++jb) {
        int j  = jb * 32 + (t >> 3);
        int i4 = (t & 7) * 4;
        float4 v = *(const float4*)&sp[(size_t)j * 128 + i0 + i4];
        Wt[(i4 + 0) * 129 + j] = v.x;
        Wt[(i4 + 1) * 129 + j] = v.y;
        Wt[(i4 + 2) * 129 + j] = v.z;
        Wt[(i4 + 3) * 129 + j] = v.w;
    }
    float acc[32];
#pragma unroll
    for (int i = 0; i < 32; ++i) acc[i] = 0.f;
    const float* lv = LV + (size_t)2 * NM * 1024 + (size_t)b * 128 * 1024 + c0;
    for (int j0 = 0; j0 < 128; j0 += 32) {
        __syncthreads();
#pragma unroll
        for (int jj8 = 0; jj8 < 8; ++jj8) {
            int j  = jj8 * 4 + (t >> 6);
            int c4 = (t & 63) * 4;
            *(float4*)&Bl[j * 260 + c4] =
                *(const float4*)&lv[(size_t)(j0 + j) * 1024 + c4];
        }
        __syncthreads();
#pragma unroll
        for (int jj = 0; jj < 32; ++jj) {
            float v = Bl[jj * 260 + t];
#pragma unroll
            for (int i = 0; i < 32; ++i)
                acc[i] = fmaf(Wt[i * 129 + j0 + jj], v, acc[i]);
        }
    }
    float* mp = ML + ((size_t)b * 128 + i0) * 1024 + c0;
#pragma unroll
    for (int i = 0; i < 32; ++i) mp[(size_t)i * 1024 + t] = acc[i];
}

// ---------------------------------------------------------------------------
// launcher
// ---------------------------------------------------------------------------
extern "C" void kernel_launch(void* const* d_in, const int* in_sizes, int n_in,
                              void* d_out, int out_size, void* d_ws, size_t ws_size,
                              hipStream_t stream)
{
    const float* x  = (const float*)d_in[0];
    const float* Wq = (const float*)d_in[1];
    const float* Wk = (const float*)d_in[2];
    const float* Wv = (const float*)d_in[3];
    float* ws   = (float*)d_ws;
    float* qkv  = ws;                               // 3*NM*1024
    float* ssqp = ws + (size_t)3 * NM * 1024;       // 12288 (padded 16384)
    float* wbuf = ssqp + 16384;                     // NM*128
    float* out  = (float*)d_out;

    bimap_kernel<<<NM, 256, 0, stream>>>(x, Wq, Wk, Wv, qkv);
    eig_fn_kernel<0><<<NMAT3 / 8, 64, 0, stream>>>(qkv, qkv, ssqp, 0.0f);
    qk_weights_kernel<<<dim3(4, 4, 32), 256, 0, stream>>>(qkv, ssqp, wbuf);
    softmax_kernel<<<32, 256, 0, stream>>>(wbuf);
    meanlog_kernel<<<dim3(4, 4, 32), 256, 0, stream>>>(wbuf, qkv, qkv);
    eig_fn_kernel<1><<<NM / 8, 64, 0, stream>>>(qkv, out, nullptr, 16.0f);
}

// Round 7
// 989.771 us; speedup vs baseline: 1.3181x; 1.3181x over previous
//
#include <hip/hip_runtime.h>
#include <math.h>

// Problem constants
#define NB   32
#define NP   128
#define NM   4096        // NB*NP matrices per type
#define NMAT3 12288      // 3*NM (Q,K,V)

typedef float v2f __attribute__((ext_vector_type(2)));

#if defined(__has_builtin)
#if __has_builtin(__builtin_elementwise_fma)
#define V2FMA(x, y, z) __builtin_elementwise_fma((x), (y), (z))
#else
#define V2FMA(x, y, z) (v2f){fmaf((x).x, (y).x, (z).x), fmaf((x).y, (y).y, (z).y)}
#endif
#else
#define V2FMA(x, y, z) (v2f){fmaf((x).x, (y).x, (z).x), fmaf((x).y, (y).y, (z).y)}
#endif

// ---------------------------------------------------------------------------
// K1: bimap — Q/K/V[b,p] = W * x[b,p] * W^T   (x: 64x64 SPD, W: 32x64)
// ---------------------------------------------------------------------------
__global__ __launch_bounds__(256) void bimap_kernel(
    const float* __restrict__ x, const float* __restrict__ Wq,
    const float* __restrict__ Wk, const float* __restrict__ Wv,
    float* __restrict__ qkv)
{
    __shared__ __align__(16) float S[64 * 64];
    __shared__ float Wl[32 * 65];
    __shared__ float T[32 * 65];
    const int tid = threadIdx.x;
    const int bp  = blockIdx.x;
    const float* xs = x + (size_t)bp * 4096;
#pragma unroll
    for (int k = 0; k < 4; ++k) {
        int idx = tid * 4 + k * 1024;
        *(float4*)&S[idx] = *(const float4*)&xs[idx];
    }
    const int o32 = tid & 31;
    const int grp = tid >> 5;
#pragma unroll 1
    for (int w = 0; w < 3; ++w) {
        const float* Wsrc = (w == 0) ? Wq : ((w == 1) ? Wk : Wv);
        __syncthreads();
#pragma unroll
        for (int k = 0; k < 8; ++k) {
            int f = tid + k * 256;
            Wl[(f >> 6) * 65 + (f & 63)] = Wsrc[f];
        }
        __syncthreads();
        {
            float acc[8];
#pragma unroll
            for (int jj = 0; jj < 8; ++jj) acc[jj] = 0.f;
            const int j0 = grp * 8;
#pragma unroll 4
            for (int i = 0; i < 64; ++i) {
                float wv = Wl[o32 * 65 + i];
                const float4 s0 = *(const float4*)&S[i * 64 + j0];
                const float4 s1 = *(const float4*)&S[i * 64 + j0 + 4];
                acc[0] = fmaf(wv, s0.x, acc[0]);
                acc[1] = fmaf(wv, s0.y, acc[1]);
                acc[2] = fmaf(wv, s0.z, acc[2]);
                acc[3] = fmaf(wv, s0.w, acc[3]);
                acc[4] = fmaf(wv, s1.x, acc[4]);
                acc[5] = fmaf(wv, s1.y, acc[5]);
                acc[6] = fmaf(wv, s1.z, acc[6]);
                acc[7] = fmaf(wv, s1.w, acc[7]);
            }
#pragma unroll
            for (int jj = 0; jj < 8; ++jj) T[o32 * 65 + j0 + jj] = acc[jj];
        }
        __syncthreads();
        {
            float oacc[4] = {0.f, 0.f, 0.f, 0.f};
            const int kcol = tid & 31;
            const int ob   = grp * 4;
#pragma unroll 4
            for (int j = 0; j < 64; ++j) {
                float wv = Wl[kcol * 65 + j];
#pragma unroll
                for (int cc = 0; cc < 4; ++cc)
                    oacc[cc] = fmaf(T[(ob + cc) * 65 + j], wv, oacc[cc]);
            }
            float* dst = qkv + ((size_t)w * NM + bp) * 1024;
#pragma unroll
            for (int cc = 0; cc < 4; ++cc)
                dst[(ob + cc) * 32 + kcol] = oacc[cc];
        }
    }
}

// ---------------------------------------------------------------------------
// K2/K5: batched symmetric eig-function, one-sided Jacobi, lane-per-pair
// systolic ordering, HALF-COLUMN per lane.
//
// Layout: wave64 = 2 matrices. Lane = (mw<<5) | (h<<4) | idx:
//   mw = matrix (0/1), h = row-half (rows 16h..16h+15), idx = pair slot.
// Lane holds a = 16 rows of column cA, b = 16 rows of column cB (v2f[8]).
// DPP rows (16 lanes) hold one (matrix, half) each, so the R5-verified
// row_ror migration schedule applies unchanged per row; gamma/alpha dots
// add one __shfl_xor(.,16) reduce (row0<->row1, row2<->row3 = same matrix).
// Both halves compute rotation params from bitwise-identical inputs in the
// same order -> identical c,s -> halves never diverge (R5-proven argument).
//
// Why: R5/R6 showed (a) allocator refuses >~100 live floats (R6: VGPR=104,
// spills, 830us), (b) kernel is latency-bound at 3 waves/SIMD (real VALU
// issue ~46%; VALUBusy gfx94x formula over-reports ~2x on CDNA4).
// Half-column: 6144 waves = 6/SIMD, live set ~55 VGPR (safe zone), chains
// halved, update/dot in packed fp32 (v_pk_fma_f32 via elementwise_fma).
// ---------------------------------------------------------------------------
__device__ __forceinline__ float ror1(float x) {   // dest i <- src (i-1)&15
    return __int_as_float(__builtin_amdgcn_mov_dpp(
        __float_as_int(x), 0x121, 0xf, 0xf, true));
}
__device__ __forceinline__ float ror15(float x) {  // dest i <- src (i+1)&15
    return __int_as_float(__builtin_amdgcn_mov_dpp(
        __float_as_int(x), 0x12F, 0xf, 0xf, true));
}

__device__ __forceinline__ float dot16(const v2f (&x)[8], const v2f (&y)[8]) {
    v2f g0 = {0.f, 0.f}, g1 = {0.f, 0.f};
#pragma unroll
    for (int j = 0; j < 8; j += 2) {
        g0 = V2FMA(x[j], y[j], g0);
        g1 = V2FMA(x[j + 1], y[j + 1], g1);
    }
    v2f g = g0 + g1;
    return g.x + g.y;
}

__device__ __forceinline__ void jupdate(v2f (&a)[8], v2f (&b)[8],
                                        float& alA, float& alB,
                                        float gm, bool doRot) {
    const float zeta = (alB - alA) * __builtin_amdgcn_rcpf(2.0f * gm);
    float tt = copysignf(__builtin_amdgcn_rcpf(
        fabsf(zeta) + __builtin_amdgcn_sqrtf(fmaf(zeta, zeta, 1.0f))), zeta);
    float cc = __builtin_amdgcn_rsqf(fmaf(tt, tt, 1.0f));
    float sn = cc * tt;
    if (!doRot) { cc = 1.0f; sn = 0.0f; }   // NaN-safe when gm==0
    const v2f c2 = {cc, cc}, sp = {sn, sn}, sm = {-sn, -sn};
#pragma unroll
    for (int j = 0; j < 8; ++j) {
        const v2f ao = a[j], bo = b[j];
        a[j] = V2FMA(c2, ao, sm * bo);
        b[j] = V2FMA(c2, bo, sp * ao);
    }
    const float cq = cc * cc, sq = sn * sn, cs2 = 2.0f * cc * sn * gm;
    const float nA = fmaf(cq, alA, fmaf(sq, alB, -cs2));
    const float nB = fmaf(sq, alA, fmaf(cq, alB, cs2));
    alA = nA; alB = nB;
}

template <int MODE>
__global__ __launch_bounds__(64) void eig_fn_kernel(
    const float* in, float* out, float* __restrict__ ssq, float shift)
{
    __shared__ __align__(16) float Uld[2][32 * 36];
    __shared__ __align__(16) float fld[2][32];
    const int tid = threadIdx.x;
    const int idx = tid & 15;            // pair slot within row
    const int h   = (tid >> 4) & 1;      // row-half of the matrix
    const int mw  = tid >> 5;            // matrix within wave (0/1)
    const bool l14 = (idx == 14), l15 = (idx == 15);
    const int cA = idx * 2, cB = idx * 2 + 1;   // initial owned columns
    const int r0 = h * 16;               // first row this lane holds
    const size_t m0 = (size_t)blockIdx.x * 2;

    const float* src = in + (m0 + mw) * 1024;
    v2f a[8], b[8];
#pragma unroll
    for (int j = 0; j < 8; ++j) {
        const int rA = r0 + 2 * j, rB = rA + 1;
        float2 lo = *(const float2*)&src[rA * 32 + cA];   // (A[rA][cA], A[rA][cB])
        float2 hi = *(const float2*)&src[rB * 32 + cA];
        v2f av = {lo.x, hi.x};
        v2f bv = {lo.y, hi.y};
        if (MODE == 1) {
            // diagonal shift: col cA is even -> row rA (even); cB odd -> rB
            if (rA == cA) av.x += shift;
            if (rB == cA) av.y += shift;   // unreachable (parity) but cheap
            if (rA == cB) bv.x += shift;   // unreachable (parity)
            if (rB == cB) bv.y += shift;
        }
        a[j] = av; b[j] = bv;
    }

    // ---- Jacobi sweeps: 31 systolic rounds/sweep ----
    for (int sweep = 0; sweep < 10; ++sweep) {
        float alA = dot16(a, a); alA += __shfl_xor(alA, 16);
        float alB = dot16(b, b); alB += __shfl_xor(alB, 16);
        bool anyrot = false;
        for (int r = 0; r < 31; ++r) {
            float gm = dot16(a, b);
            gm += __shfl_xor(gm, 16);
            const bool doRot = gm * gm > 1e-10f * (alA * alB);
            anyrot |= doRot;
            if (__any((int)doRot))
                jupdate(a, b, alA, alB, gm, doRot);
            // ---- migrate (R5-verified circle schedule, per 16-lane row) ----
            {
                const float alAg = ror1(alA), alBg = ror15(alB), alAo = alA;
                alA = l15 ? alBg : alAg;
                alB = l15 ? alB : (l14 ? alAo : alBg);
            }
#pragma unroll
            for (int j = 0; j < 8; ++j) {
                const v2f ao = a[j], bo = b[j];
                v2f t2, an;
                t2.x = ror15(bo.x); t2.y = ror15(bo.y);
                an.x = ror1(ao.x);  an.y = ror1(ao.y);
                a[j] = l15 ? t2 : an;
                v2f bn = l14 ? ao : t2;
                b[j] = l15 ? bo : bn;
            }
        }
        if (!__any((int)anyrot)) break;
    }

    // ---- finals (each column's sigma; both halves identical) ----
    float s2A = dot16(a, a); s2A += __shfl_xor(s2A, 16);
    float s2B = dot16(b, b); s2B += __shfl_xor(s2B, 16);
    const float invA = __builtin_amdgcn_rsqf(fmaxf(s2A, 1e-30f));
    const float invB = __builtin_amdgcn_rsqf(fmaxf(s2B, 1e-30f));
    float fvA, fvB;
    if (MODE == 0) {
        fvA = 0.5f * logf(fmaxf(s2A, 1e-38f));
        fvB = 0.5f * logf(fmaxf(s2B, 1e-38f));
    } else {
        fvA = expf(__builtin_amdgcn_sqrtf(s2A) - shift);
        fvB = expf(__builtin_amdgcn_sqrtf(s2B) - shift);
    }

    if (MODE == 0) {
        // ||log M||_F^2 = sum_c f_c^2 (U orthogonal to ~1e-5)
        float sq = fvA * fvA + fvB * fvB;    // h=0 and h=1 rows both hold it
#pragma unroll
        for (int off = 1; off < 16; off <<= 1) sq += __shfl_xor(sq, off);
        if ((tid & 31) == 0) ssq[m0 + mw] = sq;
    }

    // ---- reconstruction: out = U f(S) U^T, single pass (2 mat / wave) ----
#pragma unroll
    for (int j = 0; j < 8; ++j) {
        const int rA = r0 + 2 * j, rB = rA + 1;
        Uld[mw][rA * 36 + cA] = a[j].x * invA;
        Uld[mw][rB * 36 + cA] = a[j].y * invA;
        Uld[mw][rA * 36 + cB] = b[j].x * invB;
        Uld[mw][rB * 36 + cB] = b[j].y * invB;
    }
    if (h == 0) { fld[mw][cA] = fvA; fld[mw][cB] = fvB; }
    __syncthreads();

    const int c = tid & 31;              // output column; matrix = mw
    float rr[32];                        // rr[m] = f[m] * U[c][m]
    {
        const float4* urow = (const float4*)&Uld[mw][c * 36];   // 144B-aligned
        const float4* frow = (const float4*)&fld[mw][0];
#pragma unroll
        for (int m4 = 0; m4 < 8; ++m4) {
            float4 u4 = urow[m4];
            float4 f4 = frow[m4];
            rr[m4 * 4 + 0] = u4.x * f4.x;
            rr[m4 * 4 + 1] = u4.y * f4.y;
            rr[m4 * 4 + 2] = u4.z * f4.z;
            rr[m4 * 4 + 3] = u4.w * f4.w;
        }
    }
    float* dst = out + (m0 + mw) * 1024;
#pragma unroll
    for (int i = 0; i < 32; ++i) {
        float acc = 0.f;
        const float4* urow = (const float4*)&Uld[mw][i * 36];   // broadcast
#pragma unroll
        for (int m4 = 0; m4 < 8; ++m4) {
            float4 u4 = urow[m4];
            acc = fmaf(u4.x, rr[m4 * 4 + 0], acc);
            acc = fmaf(u4.y, rr[m4 * 4 + 1], acc);
            acc = fmaf(u4.z, rr[m4 * 4 + 2], acc);
            acc = fmaf(u4.w, rr[m4 * 4 + 3], acc);
        }
        dst[i * 32 + c] = acc;    // coalesced
    }
}

// ---------------------------------------------------------------------------
// K3a: weights[b,q,k] = 1/(1+log1p(max(qq+kk-2*<LQ_q,LK_k>_F, 0)))
// ---------------------------------------------------------------------------
__global__ __launch_bounds__(256) void qk_weights_kernel(
    const float* __restrict__ L, const float* __restrict__ ssq,
    float* __restrict__ wbuf)
{
    __shared__ float Aq[32 * 37];
    __shared__ float Bk[32 * 37];
    const int b  = blockIdx.z;
    const int q0 = blockIdx.y * 32;
    const int k0 = blockIdx.x * 32;
    const int tid = threadIdx.x;
    const int tx = tid & 15, ty = tid >> 4;
    const float* LQ = L + ((size_t)b * 128 + q0) * 1024;
    const float* LK = L + (size_t)NM * 1024 + ((size_t)b * 128 + k0) * 1024;
    const int lrow = tid >> 3;
    const int lm4  = (tid & 7) * 4;
    float acc00 = 0, acc01 = 0, acc10 = 0, acc11 = 0;
    for (int m0 = 0; m0 < 1024; m0 += 32) {
        __syncthreads();
        float4 va = *(const float4*)&LQ[(size_t)lrow * 1024 + m0 + lm4];
        float4 vb = *(const float4*)&LK[(size_t)lrow * 1024 + m0 + lm4];
        Aq[lrow * 37 + lm4 + 0] = va.x; Aq[lrow * 37 + lm4 + 1] = va.y;
        Aq[lrow * 37 + lm4 + 2] = va.z; Aq[lrow * 37 + lm4 + 3] = va.w;
        Bk[lrow * 37 + lm4 + 0] = vb.x; Bk[lrow * 37 + lm4 + 1] = vb.y;
        Bk[lrow * 37 + lm4 + 2] = vb.z; Bk[lrow * 37 + lm4 + 3] = vb.w;
        __syncthreads();
#pragma unroll
        for (int mm = 0; mm < 32; ++mm) {
            float a0 = Aq[(ty * 2 + 0) * 37 + mm];
            float a1 = Aq[(ty * 2 + 1) * 37 + mm];
            float b0 = Bk[(tx * 2 + 0) * 37 + mm];
            float b1 = Bk[(tx * 2 + 1) * 37 + mm];
            acc00 = fmaf(a0, b0, acc00); acc01 = fmaf(a0, b1, acc01);
            acc10 = fmaf(a1, b0, acc10); acc11 = fmaf(a1, b1, acc11);
        }
    }
    const float* qqp = ssq + (size_t)b * 128 + q0;
    const float* kkp = ssq + NM + (size_t)b * 128 + k0;
    const int q = ty * 2, k = tx * 2;
    float* wrow0 = wbuf + ((size_t)b * 128 + q0 + q) * 128 + k0 + k;
    float* wrow1 = wrow0 + 128;
    float e;
    e = fmaxf(qqp[q] + kkp[k] - 2.0f * acc00, 0.0f);
    wrow0[0] = 1.0f / (1.0f + log1pf(e));
    e = fmaxf(qqp[q] + kkp[k + 1] - 2.0f * acc01, 0.0f);
    wrow0[1] = 1.0f / (1.0f + log1pf(e));
    e = fmaxf(qqp[q + 1] + kkp[k] - 2.0f * acc10, 0.0f);
    wrow1[0] = 1.0f / (1.0f + log1pf(e));
    e = fmaxf(qqp[q + 1] + kkp[k + 1] - 2.0f * acc11, 0.0f);
    wrow1[1] = 1.0f / (1.0f + log1pf(e));
}

// ---------------------------------------------------------------------------
// K3b: in-place softmax over the QUERY axis (column-wise on [q][k])
// ---------------------------------------------------------------------------
__global__ __launch_bounds__(256) void softmax_kernel(float* __restrict__ wbuf)
{
    __shared__ float crcp[128];
    const int t = threadIdx.x;
    float* wb = wbuf + (size_t)blockIdx.x * 16384;
    if (t < 128) {
        float ssum = 0.f;
        for (int q = 0; q < 128; ++q) ssum += expf(wb[q * 128 + t]);
        crcp[t] = 1.0f / ssum;
    }
    __syncthreads();
    for (int i = t; i < 16384; i += 256)
        wb[i] = expf(wb[i]) * crcp[i & 127];
}

// ---------------------------------------------------------------------------
// K4: mean_log[b,i,:] = sum_j soft[b,j,i] * LV[b,j,:]
// ---------------------------------------------------------------------------
__global__ __launch_bounds__(256) void meanlog_kernel(
    const float* __restrict__ soft, const float* __restrict__ LV,
    float* __restrict__ ML)
{
    __shared__ float Wt[32 * 129];
    __shared__ __align__(16) float Bl[32 * 260];
    const int b  = blockIdx.z;
    const int i0 = blockIdx.y * 32;
    const int c0 = blockIdx.x * 256;
    const int t  = threadIdx.x;
    const float* sp = soft + (size_t)b * 16384;
#pragma unroll
    for (int jb = 0; jb < 4; ++jb) {
        int j  = jb * 32 + (t >> 3);
        int i4 = (t & 7) * 4;
        float4 v = *(const float4*)&sp[(size_t)j * 128 + i0 + i4];
        Wt[(i4 + 0) * 129 + j] = v.x;
        Wt[(i4 + 1) * 129 + j] = v.y;
        Wt[(i4 + 2) * 129 + j] = v.z;
        Wt[(i4 + 3) * 129 + j] = v.w;
    }
    float acc[32];
#pragma unroll
    for (int i = 0; i < 32; ++i) acc[i] = 0.f;
    const float* lv = LV + (size_t)2 * NM * 1024 + (size_t)b * 128 * 1024 + c0;
    for (int j0 = 0; j0 < 128; j0 += 32) {
        __syncthreads();
#pragma unroll
        for (int jj8 = 0; jj8 < 8; ++jj8) {
            int j  = jj8 * 4 + (t >> 6);
            int c4 = (t & 63) * 4;
            *(float4*)&Bl[j * 260 + c4] =
                *(const float4*)&lv[(size_t)(j0 + j) * 1024 + c4];
        }
        __syncthreads();
#pragma unroll
        for (int jj = 0; jj < 32; ++jj) {
            float v = Bl[jj * 260 + t];
#pragma unroll
            for (int i = 0; i < 32; ++i)
                acc[i] = fmaf(Wt[i * 129 + j0 + jj], v, acc[i]);
        }
    }
    float* mp = ML + ((size_t)b * 128 + i0) * 1024 + c0;
#pragma unroll
    for (int i = 0; i < 32; ++i) mp[(size_t)i * 1024 + t] = acc[i];
}

// ---------------------------------------------------------------------------
// launcher
// ---------------------------------------------------------------------------
extern "C" void kernel_launch(void* const* d_in, const int* in_sizes, int n_in,
                              void* d_out, int out_size, void* d_ws, size_t ws_size,
                              hipStream_t stream)
{
    const float* x  = (const float*)d_in[0];
    const float* Wq = (const float*)d_in[1];
    const float* Wk = (const float*)d_in[2];
    const float* Wv = (const float*)d_in[3];
    float* ws   = (float*)d_ws;
    float* qkv  = ws;                               // 3*NM*1024
    float* ssqp = ws + (size_t)3 * NM * 1024;       // 12288 (padded 16384)
    float* wbuf = ssqp + 16384;                     // NM*128
    float* out  = (float*)d_out;

    bimap_kernel<<<NM, 256, 0, stream>>>(x, Wq, Wk, Wv, qkv);
    eig_fn_kernel<0><<<NMAT3 / 2, 64, 0, stream>>>(qkv, qkv, ssqp, 0.0f);
    qk_weights_kernel<<<dim3(4, 4, 32), 256, 0, stream>>>(qkv, ssqp, wbuf);
    softmax_kernel<<<32, 256, 0, stream>>>(wbuf);
    meanlog_kernel<<<dim3(4, 4, 32), 256, 0, stream>>>(wbuf, qkv, qkv);
    eig_fn_kernel<1><<<NM / 2, 64, 0, stream>>>(qkv, out, nullptr, 16.0f);
}

// Round 8
// 905.204 us; speedup vs baseline: 1.4412x; 1.0934x over previous
//
#include <hip/hip_runtime.h>
#include <math.h>

// Problem constants
#define NB   32
#define NP   128
#define NM   4096        // NB*NP matrices per type
#define NMAT3 12288      // 3*NM (Q,K,V)

typedef float v2f __attribute__((ext_vector_type(2)));

#if defined(__has_builtin)
#if __has_builtin(__builtin_elementwise_fma)
#define V2FMA(x, y, z) __builtin_elementwise_fma((x), (y), (z))
#else
#define V2FMA(x, y, z) (v2f){fmaf((x).x, (y).x, (z).x), fmaf((x).y, (y).y, (z).y)}
#endif
#else
#define V2FMA(x, y, z) (v2f){fmaf((x).x, (y).x, (z).x), fmaf((x).y, (y).y, (z).y)}
#endif

// ---------------------------------------------------------------------------
// K1: bimap — Q/K/V[b,p] = W * x[b,p] * W^T   (x: 64x64 SPD, W: 32x64)
// ---------------------------------------------------------------------------
__global__ __launch_bounds__(256) void bimap_kernel(
    const float* __restrict__ x, const float* __restrict__ Wq,
    const float* __restrict__ Wk, const float* __restrict__ Wv,
    float* __restrict__ qkv)
{
    __shared__ __align__(16) float S[64 * 64];
    __shared__ float Wl[32 * 65];
    __shared__ float T[32 * 65];
    const int tid = threadIdx.x;
    const int bp  = blockIdx.x;
    const float* xs = x + (size_t)bp * 4096;
#pragma unroll
    for (int k = 0; k < 4; ++k) {
        int idx = tid * 4 + k * 1024;
        *(float4*)&S[idx] = *(const float4*)&xs[idx];
    }
    const int o32 = tid & 31;
    const int grp = tid >> 5;
#pragma unroll 1
    for (int w = 0; w < 3; ++w) {
        const float* Wsrc = (w == 0) ? Wq : ((w == 1) ? Wk : Wv);
        __syncthreads();
#pragma unroll
        for (int k = 0; k < 8; ++k) {
            int f = tid + k * 256;
            Wl[(f >> 6) * 65 + (f & 63)] = Wsrc[f];
        }
        __syncthreads();
        {
            float acc[8];
#pragma unroll
            for (int jj = 0; jj < 8; ++jj) acc[jj] = 0.f;
            const int j0 = grp * 8;
#pragma unroll 4
            for (int i = 0; i < 64; ++i) {
                float wv = Wl[o32 * 65 + i];
                const float4 s0 = *(const float4*)&S[i * 64 + j0];
                const float4 s1 = *(const float4*)&S[i * 64 + j0 + 4];
                acc[0] = fmaf(wv, s0.x, acc[0]);
                acc[1] = fmaf(wv, s0.y, acc[1]);
                acc[2] = fmaf(wv, s0.z, acc[2]);
                acc[3] = fmaf(wv, s0.w, acc[3]);
                acc[4] = fmaf(wv, s1.x, acc[4]);
                acc[5] = fmaf(wv, s1.y, acc[5]);
                acc[6] = fmaf(wv, s1.z, acc[6]);
                acc[7] = fmaf(wv, s1.w, acc[7]);
            }
#pragma unroll
            for (int jj = 0; jj < 8; ++jj) T[o32 * 65 + j0 + jj] = acc[jj];
        }
        __syncthreads();
        {
            float oacc[4] = {0.f, 0.f, 0.f, 0.f};
            const int kcol = tid & 31;
            const int ob   = grp * 4;
#pragma unroll 4
            for (int j = 0; j < 64; ++j) {
                float wv = Wl[kcol * 65 + j];
#pragma unroll
                for (int cc = 0; cc < 4; ++cc)
                    oacc[cc] = fmaf(T[(ob + cc) * 65 + j], wv, oacc[cc]);
            }
            float* dst = qkv + ((size_t)w * NM + bp) * 1024;
#pragma unroll
            for (int cc = 0; cc < 4; ++cc)
                dst[(ob + cc) * 32 + kcol] = oacc[cc];
        }
    }
}

// ---------------------------------------------------------------------------
// K2/K5: batched symmetric eig-function, one-sided Jacobi, lane-per-pair
// systolic ordering, HALF-COLUMN per lane (R7 structure).
//
// R7 post-mortem: SIMD was ~87% issue-saturated at the ACHIEVED residency,
// but residency was LDS-capped: 9728 B/block -> 16 blocks/CU (4/SIMD) while
// the grid supplies 6/SIMD. The LDS is used only in the ~1% epilogue.
// R8 changes:
//  (a) epilogue reconstructs ONE matrix at a time -> LDS 4736 B -> LDS cap
//      33 blocks/CU, all 24 grid waves/CU resident (6/SIMD).
//  (b) two-threshold sweep break: rotate at gamma^2 > 1e-10*ab, but break
//      when the whole sweep saw no gamma^2 > 1e-7*ab (post-sweep residual
//      ~angle^2 ~ 1e-8: converged). Removes the all-quiescent confirm sweep.
// ---------------------------------------------------------------------------
__device__ __forceinline__ float ror1(float x) {   // dest i <- src (i-1)&15
    return __int_as_float(__builtin_amdgcn_mov_dpp(
        __float_as_int(x), 0x121, 0xf, 0xf, true));
}
__device__ __forceinline__ float ror15(float x) {  // dest i <- src (i+1)&15
    return __int_as_float(__builtin_amdgcn_mov_dpp(
        __float_as_int(x), 0x12F, 0xf, 0xf, true));
}

__device__ __forceinline__ float dot16(const v2f (&x)[8], const v2f (&y)[8]) {
    v2f g0 = {0.f, 0.f}, g1 = {0.f, 0.f};
#pragma unroll
    for (int j = 0; j < 8; j += 2) {
        g0 = V2FMA(x[j], y[j], g0);
        g1 = V2FMA(x[j + 1], y[j + 1], g1);
    }
    v2f g = g0 + g1;
    return g.x + g.y;
}

__device__ __forceinline__ void jupdate(v2f (&a)[8], v2f (&b)[8],
                                        float& alA, float& alB,
                                        float gm, bool doRot) {
    const float zeta = (alB - alA) * __builtin_amdgcn_rcpf(2.0f * gm);
    float tt = copysignf(__builtin_amdgcn_rcpf(
        fabsf(zeta) + __builtin_amdgcn_sqrtf(fmaf(zeta, zeta, 1.0f))), zeta);
    float cc = __builtin_amdgcn_rsqf(fmaf(tt, tt, 1.0f));
    float sn = cc * tt;
    if (!doRot) { cc = 1.0f; sn = 0.0f; }   // NaN-safe when gm==0
    const v2f c2 = {cc, cc}, sp = {sn, sn}, sm = {-sn, -sn};
#pragma unroll
    for (int j = 0; j < 8; ++j) {
        const v2f ao = a[j], bo = b[j];
        a[j] = V2FMA(c2, ao, sm * bo);
        b[j] = V2FMA(c2, bo, sp * ao);
    }
    const float cq = cc * cc, sq = sn * sn, cs2 = 2.0f * cc * sn * gm;
    const float nA = fmaf(cq, alA, fmaf(sq, alB, -cs2));
    const float nB = fmaf(sq, alA, fmaf(cq, alB, cs2));
    alA = nA; alB = nB;
}

template <int MODE>
__global__ __launch_bounds__(64) void eig_fn_kernel(
    const float* in, float* out, float* __restrict__ ssq, float shift)
{
    __shared__ __align__(16) float Uld[32 * 36];   // ONE matrix (4.6 KB)
    __shared__ __align__(16) float fld[32];
    const int tid = threadIdx.x;
    const int idx = tid & 15;            // pair slot within row
    const int h   = (tid >> 4) & 1;      // row-half of the matrix
    const int mw  = tid >> 5;            // matrix within wave (0/1)
    const bool l14 = (idx == 14), l15 = (idx == 15);
    const int cA = idx * 2, cB = idx * 2 + 1;   // initial owned columns
    const int r0 = h * 16;               // first row this lane holds
    const size_t m0 = (size_t)blockIdx.x * 2;

    const float* src = in + (m0 + mw) * 1024;
    v2f a[8], b[8];
#pragma unroll
    for (int j = 0; j < 8; ++j) {
        const int rA = r0 + 2 * j, rB = rA + 1;
        float2 lo = *(const float2*)&src[rA * 32 + cA];   // (A[rA][cA], A[rA][cB])
        float2 hi = *(const float2*)&src[rB * 32 + cA];
        v2f av = {lo.x, hi.x};
        v2f bv = {lo.y, hi.y};
        if (MODE == 1) {
            if (rA == cA) av.x += shift;
            if (rB == cA) av.y += shift;   // unreachable (parity) but cheap
            if (rA == cB) bv.x += shift;   // unreachable (parity)
            if (rB == cB) bv.y += shift;
        }
        a[j] = av; b[j] = bv;
    }

    // ---- Jacobi sweeps: 31 systolic rounds/sweep ----
    for (int sweep = 0; sweep < 10; ++sweep) {
        float alA = dot16(a, a); alA += __shfl_xor(alA, 16);
        float alB = dot16(b, b); alB += __shfl_xor(alB, 16);
        bool bigrot = false;
        for (int r = 0; r < 31; ++r) {
            float gm = dot16(a, b);
            gm += __shfl_xor(gm, 16);
            const float t  = alA * alB;
            const float g2 = gm * gm;
            const bool doRot = g2 > 1e-10f * t;
            bigrot |= (g2 > 1e-7f * t);
            if (__any((int)doRot))
                jupdate(a, b, alA, alB, gm, doRot);
            // ---- migrate (R5-verified circle schedule, per 16-lane row) ----
            {
                const float alAg = ror1(alA), alBg = ror15(alB), alAo = alA;
                alA = l15 ? alBg : alAg;
                alB = l15 ? alB : (l14 ? alAo : alBg);
            }
#pragma unroll
            for (int j = 0; j < 8; ++j) {
                const v2f ao = a[j], bo = b[j];
                v2f t2, an;
                t2.x = ror15(bo.x); t2.y = ror15(bo.y);
                an.x = ror1(ao.x);  an.y = ror1(ao.y);
                a[j] = l15 ? t2 : an;
                v2f bn = l14 ? ao : t2;
                b[j] = l15 ? bo : bn;
            }
        }
        if (!__any((int)bigrot)) break;   // sweep saw only sub-1e-7 angles
    }

    // ---- finals (each column's sigma; both halves identical) ----
    float s2A = dot16(a, a); s2A += __shfl_xor(s2A, 16);
    float s2B = dot16(b, b); s2B += __shfl_xor(s2B, 16);
    const float invA = __builtin_amdgcn_rsqf(fmaxf(s2A, 1e-30f));
    const float invB = __builtin_amdgcn_rsqf(fmaxf(s2B, 1e-30f));
    float fvA, fvB;
    if (MODE == 0) {
        fvA = 0.5f * logf(fmaxf(s2A, 1e-38f));
        fvB = 0.5f * logf(fmaxf(s2B, 1e-38f));
    } else {
        fvA = expf(__builtin_amdgcn_sqrtf(s2A) - shift);
        fvB = expf(__builtin_amdgcn_sqrtf(s2B) - shift);
    }

    if (MODE == 0) {
        // ||log M||_F^2 = sum_c f_c^2 (U orthogonal to ~1e-5)
        float sq = fvA * fvA + fvB * fvB;    // h=0 and h=1 rows both hold it
#pragma unroll
        for (int off = 1; off < 16; off <<= 1) sq += __shfl_xor(sq, off);
        if ((tid & 31) == 0) ssq[m0 + mw] = sq;
    }

    // ---- reconstruction: out = U f(S) U^T, ONE matrix per pass ----
    const int c  = tid & 31;             // output column
    const int hh = tid >> 5;             // output row-half
#pragma unroll 1
    for (int p = 0; p < 2; ++p) {
        __syncthreads();   // Uld reuse between passes
        if (mw == p) {
#pragma unroll
            for (int j = 0; j < 8; ++j) {
                const int rA = r0 + 2 * j, rB = rA + 1;
                Uld[rA * 36 + cA] = a[j].x * invA;
                Uld[rB * 36 + cA] = a[j].y * invA;
                Uld[rA * 36 + cB] = b[j].x * invB;
                Uld[rB * 36 + cB] = b[j].y * invB;
            }
            if (h == 0) { fld[cA] = fvA; fld[cB] = fvB; }
        }
        __syncthreads();
        float rr[32];                    // rr[m] = f[m] * U[c][m]
        {
            const float4* urow = (const float4*)&Uld[c * 36];
            const float4* frow = (const float4*)&fld[0];
#pragma unroll
            for (int m4 = 0; m4 < 8; ++m4) {
                float4 u4 = urow[m4];
                float4 f4 = frow[m4];
                rr[m4 * 4 + 0] = u4.x * f4.x;
                rr[m4 * 4 + 1] = u4.y * f4.y;
                rr[m4 * 4 + 2] = u4.z * f4.z;
                rr[m4 * 4 + 3] = u4.w * f4.w;
            }
        }
        float* dst = out + (m0 + p) * 1024;
#pragma unroll
        for (int i = 0; i < 16; ++i) {
            const int row = hh * 16 + i;
            float acc = 0.f;
            const float4* urow = (const float4*)&Uld[row * 36];  // broadcast
#pragma unroll
            for (int m4 = 0; m4 < 8; ++m4) {
                float4 u4 = urow[m4];
                acc = fmaf(u4.x, rr[m4 * 4 + 0], acc);
                acc = fmaf(u4.y, rr[m4 * 4 + 1], acc);
                acc = fmaf(u4.z, rr[m4 * 4 + 2], acc);
                acc = fmaf(u4.w, rr[m4 * 4 + 3], acc);
            }
            dst[row * 32 + c] = acc;     // coalesced per half-wave
        }
    }
}

// ---------------------------------------------------------------------------
// K3a: weights[b,q,k] = 1/(1+log1p(max(qq+kk-2*<LQ_q,LK_k>_F, 0)))
// ---------------------------------------------------------------------------
__global__ __launch_bounds__(256) void qk_weights_kernel(
    const float* __restrict__ L, const float* __restrict__ ssq,
    float* __restrict__ wbuf)
{
    __shared__ float Aq[32 * 37];
    __shared__ float Bk[32 * 37];
    const int b  = blockIdx.z;
    const int q0 = blockIdx.y * 32;
    const int k0 = blockIdx.x * 32;
    const int tid = threadIdx.x;
    const int tx = tid & 15, ty = tid >> 4;
    const float* LQ = L + ((size_t)b * 128 + q0) * 1024;
    const float* LK = L + (size_t)NM * 1024 + ((size_t)b * 128 + k0) * 1024;
    const int lrow = tid >> 3;
    const int lm4  = (tid & 7) * 4;
    float acc00 = 0, acc01 = 0, acc10 = 0, acc11 = 0;
    for (int m0 = 0; m0 < 1024; m0 += 32) {
        __syncthreads();
        float4 va = *(const float4*)&LQ[(size_t)lrow * 1024 + m0 + lm4];
        float4 vb = *(const float4*)&LK[(size_t)lrow * 1024 + m0 + lm4];
        Aq[lrow * 37 + lm4 + 0] = va.x; Aq[lrow * 37 + lm4 + 1] = va.y;
        Aq[lrow * 37 + lm4 + 2] = va.z; Aq[lrow * 37 + lm4 + 3] = va.w;
        Bk[lrow * 37 + lm4 + 0] = vb.x; Bk[lrow * 37 + lm4 + 1] = vb.y;
        Bk[lrow * 37 + lm4 + 2] = vb.z; Bk[lrow * 37 + lm4 + 3] = vb.w;
        __syncthreads();
#pragma unroll
        for (int mm = 0; mm < 32; ++mm) {
            float a0 = Aq[(ty * 2 + 0) * 37 + mm];
            float a1 = Aq[(ty * 2 + 1) * 37 + mm];
            float b0 = Bk[(tx * 2 + 0) * 37 + mm];
            float b1 = Bk[(tx * 2 + 1) * 37 + mm];
            acc00 = fmaf(a0, b0, acc00); acc01 = fmaf(a0, b1, acc01);
            acc10 = fmaf(a1, b0, acc10); acc11 = fmaf(a1, b1, acc11);
        }
    }
    const float* qqp = ssq + (size_t)b * 128 + q0;
    const float* kkp = ssq + NM + (size_t)b * 128 + k0;
    const int q = ty * 2, k = tx * 2;
    float* wrow0 = wbuf + ((size_t)b * 128 + q0 + q) * 128 + k0 + k;
    float* wrow1 = wrow0 + 128;
    float e;
    e = fmaxf(qqp[q] + kkp[k] - 2.0f * acc00, 0.0f);
    wrow0[0] = 1.0f / (1.0f + log1pf(e));
    e = fmaxf(qqp[q] + kkp[k + 1] - 2.0f * acc01, 0.0f);
    wrow0[1] = 1.0f / (1.0f + log1pf(e));
    e = fmaxf(qqp[q + 1] + kkp[k] - 2.0f * acc10, 0.0f);
    wrow1[0] = 1.0f / (1.0f + log1pf(e));
    e = fmaxf(qqp[q + 1] + kkp[k + 1] - 2.0f * acc11, 0.0f);
    wrow1[1] = 1.0f / (1.0f + log1pf(e));
}

// ---------------------------------------------------------------------------
// K3b: in-place softmax over the QUERY axis (column-wise on [q][k])
// ---------------------------------------------------------------------------
__global__ __launch_bounds__(256) void softmax_kernel(float* __restrict__ wbuf)
{
    __shared__ float crcp[128];
    const int t = threadIdx.x;
    float* wb = wbuf + (size_t)blockIdx.x * 16384;
    if (t < 128) {
        float ssum = 0.f;
        for (int q = 0; q < 128; ++q) ssum += expf(wb[q * 128 + t]);
        crcp[t] = 1.0f / ssum;
    }
    __syncthreads();
    for (int i = t; i < 16384; i += 256)
        wb[i] = expf(wb[i]) * crcp[i & 127];
}

// ---------------------------------------------------------------------------
// K4: mean_log[b,i,:] = sum_j soft[b,j,i] * LV[b,j,:]
// ---------------------------------------------------------------------------
__global__ __launch_bounds__(256) void meanlog_kernel(
    const float* __restrict__ soft, const float* __restrict__ LV,
    float* __restrict__ ML)
{
    __shared__ float Wt[32 * 129];
    __shared__ __align__(16) float Bl[32 * 260];
    const int b  = blockIdx.z;
    const int i0 = blockIdx.y * 32;
    const int c0 = blockIdx.x * 256;
    const int t  = threadIdx.x;
    const float* sp = soft + (size_t)b * 16384;
#pragma unroll
    for (int jb = 0; jb < 4; ++jb) {
        int j  = jb * 32 + (t >> 3);
        int i4 = (t & 7) * 4;
        float4 v = *(const float4*)&sp[(size_t)j * 128 + i0 + i4];
        Wt[(i4 + 0) * 129 + j] = v.x;
        Wt[(i4 + 1) * 129 + j] = v.y;
        Wt[(i4 + 2) * 129 + j] = v.z;
        Wt[(i4 + 3) * 129 + j] = v.w;
    }
    float acc[32];
#pragma unroll
    for (int i = 0; i < 32; ++i) acc[i] = 0.f;
    const float* lv = LV + (size_t)2 * NM * 1024 + (size_t)b * 128 * 1024 + c0;
    for (int j0 = 0; j0 < 128; j0 += 32) {
        __syncthreads();
#pragma unroll
        for (int jj8 = 0; jj8 < 8; ++jj8) {
            int j  = jj8 * 4 + (t >> 6);
            int c4 = (t & 63) * 4;
            *(float4*)&Bl[j * 260 + c4] =
                *(const float4*)&lv[(size_t)(j0 + j) * 1024 + c4];
        }
        __syncthreads();
#pragma unroll
        for (int jj = 0; jj < 32; ++jj) {
            float v = Bl[jj * 260 + t];
#pragma unroll
            for (int i = 0; i < 32; ++i)
                acc[i] = fmaf(Wt[i * 129 + j0 + jj], v, acc[i]);
        }
    }
    float* mp = ML + ((size_t)b * 128 + i0) * 1024 + c0;
#pragma unroll
    for (int i = 0; i < 32; ++i) mp[(size_t)i * 1024 + t] = acc[i];
}

// ---------------------------------------------------------------------------
// launcher
// ---------------------------------------------------------------------------
extern "C" void kernel_launch(void* const* d_in, const int* in_sizes, int n_in,
                              void* d_out, int out_size, void* d_ws, size_t ws_size,
                              hipStream_t stream)
{
    const float* x  = (const float*)d_in[0];
    const float* Wq = (const float*)d_in[1];
    const float* Wk = (const float*)d_in[2];
    const float* Wv = (const float*)d_in[3];
    float* ws   = (float*)d_ws;
    float* qkv  = ws;                               // 3*NM*1024
    float* ssqp = ws + (size_t)3 * NM * 1024;       // 12288 (padded 16384)
    float* wbuf = ssqp + 16384;                     // NM*128
    float* out  = (float*)d_out;

    bimap_kernel<<<NM, 256, 0, stream>>>(x, Wq, Wk, Wv, qkv);
    eig_fn_kernel<0><<<NMAT3 / 2, 64, 0, stream>>>(qkv, qkv, ssqp, 0.0f);
    qk_weights_kernel<<<dim3(4, 4, 32), 256, 0, stream>>>(qkv, ssqp, wbuf);
    softmax_kernel<<<32, 256, 0, stream>>>(wbuf);
    meanlog_kernel<<<dim3(4, 4, 32), 256, 0, stream>>>(wbuf, qkv, qkv);
    eig_fn_kernel<1><<<NM / 2, 64, 0, stream>>>(qkv, out, nullptr, 16.0f);
}

// Round 9
// 846.608 us; speedup vs baseline: 1.5409x; 1.0692x over previous
//
#include <hip/hip_runtime.h>
#include <math.h>

// Problem constants
#define NB   32
#define NP   128
#define NM   4096        // NB*NP matrices per type
#define NMAT3 12288      // 3*NM (Q,K,V)

typedef float v2f __attribute__((ext_vector_type(2)));

#if defined(__has_builtin)
#if __has_builtin(__builtin_elementwise_fma)
#define V2FMA(x, y, z) __builtin_elementwise_fma((x), (y), (z))
#else
#define V2FMA(x, y, z) (v2f){fmaf((x).x, (y).x, (z).x), fmaf((x).y, (y).y, (z).y)}
#endif
#else
#define V2FMA(x, y, z) (v2f){fmaf((x).x, (y).x, (z).x), fmaf((x).y, (y).y, (z).y)}
#endif

// ---------------------------------------------------------------------------
// K1: bimap — Q/K/V[b,p] = W * x[b,p] * W^T   (x: 64x64 SPD, W: 32x64)
// ---------------------------------------------------------------------------
__global__ __launch_bounds__(256) void bimap_kernel(
    const float* __restrict__ x, const float* __restrict__ Wq,
    const float* __restrict__ Wk, const float* __restrict__ Wv,
    float* __restrict__ qkv)
{
    __shared__ __align__(16) float S[64 * 64];
    __shared__ float Wl[32 * 65];
    __shared__ float T[32 * 65];
    const int tid = threadIdx.x;
    const int bp  = blockIdx.x;
    const float* xs = x + (size_t)bp * 4096;
#pragma unroll
    for (int k = 0; k < 4; ++k) {
        int idx = tid * 4 + k * 1024;
        *(float4*)&S[idx] = *(const float4*)&xs[idx];
    }
    const int o32 = tid & 31;
    const int grp = tid >> 5;
#pragma unroll 1
    for (int w = 0; w < 3; ++w) {
        const float* Wsrc = (w == 0) ? Wq : ((w == 1) ? Wk : Wv);
        __syncthreads();
#pragma unroll
        for (int k = 0; k < 8; ++k) {
            int f = tid + k * 256;
            Wl[(f >> 6) * 65 + (f & 63)] = Wsrc[f];
        }
        __syncthreads();
        {
            float acc[8];
#pragma unroll
            for (int jj = 0; jj < 8; ++jj) acc[jj] = 0.f;
            const int j0 = grp * 8;
#pragma unroll 4
            for (int i = 0; i < 64; ++i) {
                float wv = Wl[o32 * 65 + i];
                const float4 s0 = *(const float4*)&S[i * 64 + j0];
                const float4 s1 = *(const float4*)&S[i * 64 + j0 + 4];
                acc[0] = fmaf(wv, s0.x, acc[0]);
                acc[1] = fmaf(wv, s0.y, acc[1]);
                acc[2] = fmaf(wv, s0.z, acc[2]);
                acc[3] = fmaf(wv, s0.w, acc[3]);
                acc[4] = fmaf(wv, s1.x, acc[4]);
                acc[5] = fmaf(wv, s1.y, acc[5]);
                acc[6] = fmaf(wv, s1.z, acc[6]);
                acc[7] = fmaf(wv, s1.w, acc[7]);
            }
#pragma unroll
            for (int jj = 0; jj < 8; ++jj) T[o32 * 65 + j0 + jj] = acc[jj];
        }
        __syncthreads();
        {
            float oacc[4] = {0.f, 0.f, 0.f, 0.f};
            const int kcol = tid & 31;
            const int ob   = grp * 4;
#pragma unroll 4
            for (int j = 0; j < 64; ++j) {
                float wv = Wl[kcol * 65 + j];
#pragma unroll
                for (int cc = 0; cc < 4; ++cc)
                    oacc[cc] = fmaf(T[(ob + cc) * 65 + j], wv, oacc[cc]);
            }
            float* dst = qkv + ((size_t)w * NM + bp) * 1024;
#pragma unroll
            for (int cc = 0; cc < 4; ++cc)
                dst[(ob + cc) * 32 + kcol] = oacc[cc];
        }
    }
}

// ---------------------------------------------------------------------------
// K2/K5: batched symmetric eig-function, one-sided Jacobi, lane-per-pair
// systolic ordering, HALF-COLUMN per lane (R7/R8 wave structure), packed in
// 256-THREAD BLOCKS (4 independent waves, 8 matrices/block).
//
// R8 post-mortem: occupancy stuck at ~34% across LDS 9.7KB->5.1KB because
// CDNA caps WORKGROUPS per CU (~16 slots) — with 1-wave WGs that's <=16
// waves/CU no matter what. Fix: 4 waves per WG -> 6 blocks/CU -> 24
// waves/CU (6/SIMD). Per-wave LDS slices (4 x 4.75KB); __syncthreads in
// the tiny epilogue only (cost ~ sweep-count variance across the 4 waves).
//
// Convergence (R8-verified): rotate at gamma^2 > 1e-10*ab; break when the
// whole sweep saw no gamma^2 > 1e-7*ab.
// MODE 0: f=log(lambda), writes ssq = sum f^2 = ||log M||_F^2
// MODE 1: input += shift*I on load, f=exp(lambda-shift)
// ---------------------------------------------------------------------------
__device__ __forceinline__ float ror1(float x) {   // dest i <- src (i-1)&15
    return __int_as_float(__builtin_amdgcn_mov_dpp(
        __float_as_int(x), 0x121, 0xf, 0xf, true));
}
__device__ __forceinline__ float ror15(float x) {  // dest i <- src (i+1)&15
    return __int_as_float(__builtin_amdgcn_mov_dpp(
        __float_as_int(x), 0x12F, 0xf, 0xf, true));
}

__device__ __forceinline__ float dot16(const v2f (&x)[8], const v2f (&y)[8]) {
    v2f g0 = {0.f, 0.f}, g1 = {0.f, 0.f};
#pragma unroll
    for (int j = 0; j < 8; j += 2) {
        g0 = V2FMA(x[j], y[j], g0);
        g1 = V2FMA(x[j + 1], y[j + 1], g1);
    }
    v2f g = g0 + g1;
    return g.x + g.y;
}

__device__ __forceinline__ void jupdate(v2f (&a)[8], v2f (&b)[8],
                                        float& alA, float& alB,
                                        float gm, bool doRot) {
    const float zeta = (alB - alA) * __builtin_amdgcn_rcpf(2.0f * gm);
    float tt = copysignf(__builtin_amdgcn_rcpf(
        fabsf(zeta) + __builtin_amdgcn_sqrtf(fmaf(zeta, zeta, 1.0f))), zeta);
    float cc = __builtin_amdgcn_rsqf(fmaf(tt, tt, 1.0f));
    float sn = cc * tt;
    if (!doRot) { cc = 1.0f; sn = 0.0f; }   // NaN-safe when gm==0
    const v2f c2 = {cc, cc}, sp = {sn, sn}, sm = {-sn, -sn};
#pragma unroll
    for (int j = 0; j < 8; ++j) {
        const v2f ao = a[j], bo = b[j];
        a[j] = V2FMA(c2, ao, sm * bo);
        b[j] = V2FMA(c2, bo, sp * ao);
    }
    const float cq = cc * cc, sq = sn * sn, cs2 = 2.0f * cc * sn * gm;
    const float nA = fmaf(cq, alA, fmaf(sq, alB, -cs2));
    const float nB = fmaf(sq, alA, fmaf(cq, alB, cs2));
    alA = nA; alB = nB;
}

template <int MODE>
__global__ __launch_bounds__(256) void eig_fn_kernel(
    const float* in, float* out, float* __restrict__ ssq, float shift)
{
    __shared__ __align__(16) float Uld[4][32 * 36];   // per-wave slice
    __shared__ __align__(16) float fld[4][32];
    const int tid  = threadIdx.x;
    const int wv   = tid >> 6;           // wave in block (0..3)
    const int lane = tid & 63;
    const int idx  = lane & 15;          // pair slot within row
    const int h    = (lane >> 4) & 1;    // row-half of the matrix
    const int mw   = lane >> 5;          // matrix within wave (0/1)
    const bool l14 = (idx == 14), l15 = (idx == 15);
    const int cA = idx * 2, cB = idx * 2 + 1;   // initial owned columns
    const int r0 = h * 16;               // first row this lane holds
    const size_t m0 = (size_t)blockIdx.x * 8 + wv * 2;

    const float* src = in + (m0 + mw) * 1024;
    v2f a[8], b[8];
#pragma unroll
    for (int j = 0; j < 8; ++j) {
        const int rA = r0 + 2 * j, rB = rA + 1;
        float2 lo = *(const float2*)&src[rA * 32 + cA];   // (A[rA][cA], A[rA][cB])
        float2 hi = *(const float2*)&src[rB * 32 + cA];
        v2f av = {lo.x, hi.x};
        v2f bv = {lo.y, hi.y};
        if (MODE == 1) {
            if (rA == cA) av.x += shift;
            if (rB == cA) av.y += shift;   // unreachable (parity) but cheap
            if (rA == cB) bv.x += shift;   // unreachable (parity)
            if (rB == cB) bv.y += shift;
        }
        a[j] = av; b[j] = bv;
    }

    // ---- Jacobi sweeps: 31 systolic rounds/sweep (all per-wave) ----
    for (int sweep = 0; sweep < 10; ++sweep) {
        float alA = dot16(a, a); alA += __shfl_xor(alA, 16);
        float alB = dot16(b, b); alB += __shfl_xor(alB, 16);
        bool bigrot = false;
        for (int r = 0; r < 31; ++r) {
            float gm = dot16(a, b);
            gm += __shfl_xor(gm, 16);
            const float t  = alA * alB;
            const float g2 = gm * gm;
            const bool doRot = g2 > 1e-10f * t;
            bigrot |= (g2 > 1e-7f * t);
            if (__any((int)doRot))
                jupdate(a, b, alA, alB, gm, doRot);
            // ---- migrate (R5-verified circle schedule, per 16-lane row) ----
            {
                const float alAg = ror1(alA), alBg = ror15(alB), alAo = alA;
                alA = l15 ? alBg : alAg;
                alB = l15 ? alB : (l14 ? alAo : alBg);
            }
#pragma unroll
            for (int j = 0; j < 8; ++j) {
                const v2f ao = a[j], bo = b[j];
                v2f t2, an;
                t2.x = ror15(bo.x); t2.y = ror15(bo.y);
                an.x = ror1(ao.x);  an.y = ror1(ao.y);
                a[j] = l15 ? t2 : an;
                v2f bn = l14 ? ao : t2;
                b[j] = l15 ? bo : bn;
            }
        }
        if (!__any((int)bigrot)) break;   // sweep saw only sub-1e-7 angles
    }

    // ---- finals (each column's sigma; both halves identical) ----
    float s2A = dot16(a, a); s2A += __shfl_xor(s2A, 16);
    float s2B = dot16(b, b); s2B += __shfl_xor(s2B, 16);
    const float invA = __builtin_amdgcn_rsqf(fmaxf(s2A, 1e-30f));
    const float invB = __builtin_amdgcn_rsqf(fmaxf(s2B, 1e-30f));
    float fvA, fvB;
    if (MODE == 0) {
        fvA = 0.5f * logf(fmaxf(s2A, 1e-38f));
        fvB = 0.5f * logf(fmaxf(s2B, 1e-38f));
    } else {
        fvA = expf(__builtin_amdgcn_sqrtf(s2A) - shift);
        fvB = expf(__builtin_amdgcn_sqrtf(s2B) - shift);
    }

    if (MODE == 0) {
        // ||log M||_F^2 = sum_c f_c^2 (U orthogonal to ~1e-5)
        float sq = fvA * fvA + fvB * fvB;    // h=0 and h=1 rows both hold it
#pragma unroll
        for (int off = 1; off < 16; off <<= 1) sq += __shfl_xor(sq, off);
        if ((lane & 31) == 0) ssq[m0 + mw] = sq;
    }

    // ---- reconstruction: out = U f(S) U^T, ONE matrix per pass per wave ----
    const int c  = lane & 31;            // output column
    const int hh = lane >> 5;            // output row-half
    float* Uw = &Uld[wv][0];
    float* fw = &fld[wv][0];
#pragma unroll 1
    for (int p = 0; p < 2; ++p) {
        __syncthreads();   // Uld reuse between passes (block-wide; epilogue tiny)
        if (mw == p) {
#pragma unroll
            for (int j = 0; j < 8; ++j) {
                const int rA = r0 + 2 * j, rB = rA + 1;
                Uw[rA * 36 + cA] = a[j].x * invA;
                Uw[rB * 36 + cA] = a[j].y * invA;
                Uw[rA * 36 + cB] = b[j].x * invB;
                Uw[rB * 36 + cB] = b[j].y * invB;
            }
            if (h == 0) { fw[cA] = fvA; fw[cB] = fvB; }
        }
        __syncthreads();
        float rr[32];                    // rr[m] = f[m] * U[c][m]
        {
            const float4* urow = (const float4*)&Uw[c * 36];
            const float4* frow = (const float4*)&fw[0];
#pragma unroll
            for (int m4 = 0; m4 < 8; ++m4) {
                float4 u4 = urow[m4];
                float4 f4 = frow[m4];
                rr[m4 * 4 + 0] = u4.x * f4.x;
                rr[m4 * 4 + 1] = u4.y * f4.y;
                rr[m4 * 4 + 2] = u4.z * f4.z;
                rr[m4 * 4 + 3] = u4.w * f4.w;
            }
        }
        float* dst = out + (m0 + p) * 1024;
#pragma unroll
        for (int i = 0; i < 16; ++i) {
            const int row = hh * 16 + i;
            float acc = 0.f;
            const float4* urow = (const float4*)&Uw[row * 36];  // broadcast
#pragma unroll
            for (int m4 = 0; m4 < 8; ++m4) {
                float4 u4 = urow[m4];
                acc = fmaf(u4.x, rr[m4 * 4 + 0], acc);
                acc = fmaf(u4.y, rr[m4 * 4 + 1], acc);
                acc = fmaf(u4.z, rr[m4 * 4 + 2], acc);
                acc = fmaf(u4.w, rr[m4 * 4 + 3], acc);
            }
            dst[row * 32 + c] = acc;     // coalesced per half-wave
        }
    }
}

// ---------------------------------------------------------------------------
// K3a: weights[b,q,k] = 1/(1+log1p(max(qq+kk-2*<LQ_q,LK_k>_F, 0)))
// ---------------------------------------------------------------------------
__global__ __launch_bounds__(256) void qk_weights_kernel(
    const float* __restrict__ L, const float* __restrict__ ssq,
    float* __restrict__ wbuf)
{
    __shared__ float Aq[32 * 37];
    __shared__ float Bk[32 * 37];
    const int b  = blockIdx.z;
    const int q0 = blockIdx.y * 32;
    const int k0 = blockIdx.x * 32;
    const int tid = threadIdx.x;
    const int tx = tid & 15, ty = tid >> 4;
    const float* LQ = L + ((size_t)b * 128 + q0) * 1024;
    const float* LK = L + (size_t)NM * 1024 + ((size_t)b * 128 + k0) * 1024;
    const int lrow = tid >> 3;
    const int lm4  = (tid & 7) * 4;
    float acc00 = 0, acc01 = 0, acc10 = 0, acc11 = 0;
    for (int m0 = 0; m0 < 1024; m0 += 32) {
        __syncthreads();
        float4 va = *(const float4*)&LQ[(size_t)lrow * 1024 + m0 + lm4];
        float4 vb = *(const float4*)&LK[(size_t)lrow * 1024 + m0 + lm4];
        Aq[lrow * 37 + lm4 + 0] = va.x; Aq[lrow * 37 + lm4 + 1] = va.y;
        Aq[lrow * 37 + lm4 + 2] = va.z; Aq[lrow * 37 + lm4 + 3] = va.w;
        Bk[lrow * 37 + lm4 + 0] = vb.x; Bk[lrow * 37 + lm4 + 1] = vb.y;
        Bk[lrow * 37 + lm4 + 2] = vb.z; Bk[lrow * 37 + lm4 + 3] = vb.w;
        __syncthreads();
#pragma unroll
        for (int mm = 0; mm < 32; ++mm) {
            float a0 = Aq[(ty * 2 + 0) * 37 + mm];
            float a1 = Aq[(ty * 2 + 1) * 37 + mm];
            float b0 = Bk[(tx * 2 + 0) * 37 + mm];
            float b1 = Bk[(tx * 2 + 1) * 37 + mm];
            acc00 = fmaf(a0, b0, acc00); acc01 = fmaf(a0, b1, acc01);
            acc10 = fmaf(a1, b0, acc10); acc11 = fmaf(a1, b1, acc11);
        }
    }
    const float* qqp = ssq + (size_t)b * 128 + q0;
    const float* kkp = ssq + NM + (size_t)b * 128 + k0;
    const int q = ty * 2, k = tx * 2;
    float* wrow0 = wbuf + ((size_t)b * 128 + q0 + q) * 128 + k0 + k;
    float* wrow1 = wrow0 + 128;
    float e;
    e = fmaxf(qqp[q] + kkp[k] - 2.0f * acc00, 0.0f);
    wrow0[0] = 1.0f / (1.0f + log1pf(e));
    e = fmaxf(qqp[q] + kkp[k + 1] - 2.0f * acc01, 0.0f);
    wrow0[1] = 1.0f / (1.0f + log1pf(e));
    e = fmaxf(qqp[q + 1] + kkp[k] - 2.0f * acc10, 0.0f);
    wrow1[0] = 1.0f / (1.0f + log1pf(e));
    e = fmaxf(qqp[q + 1] + kkp[k + 1] - 2.0f * acc11, 0.0f);
    wrow1[1] = 1.0f / (1.0f + log1pf(e));
}

// ---------------------------------------------------------------------------
// K3b: in-place softmax over the QUERY axis (column-wise on [q][k])
// ---------------------------------------------------------------------------
__global__ __launch_bounds__(256) void softmax_kernel(float* __restrict__ wbuf)
{
    __shared__ float crcp[128];
    const int t = threadIdx.x;
    float* wb = wbuf + (size_t)blockIdx.x * 16384;
    if (t < 128) {
        float ssum = 0.f;
        for (int q = 0; q < 128; ++q) ssum += expf(wb[q * 128 + t]);
        crcp[t] = 1.0f / ssum;
    }
    __syncthreads();
    for (int i = t; i < 16384; i += 256)
        wb[i] = expf(wb[i]) * crcp[i & 127];
}

// ---------------------------------------------------------------------------
// K4: mean_log[b,i,:] = sum_j soft[b,j,i] * LV[b,j,:]
// ---------------------------------------------------------------------------
__global__ __launch_bounds__(256) void meanlog_kernel(
    const float* __restrict__ soft, const float* __restrict__ LV,
    float* __restrict__ ML)
{
    __shared__ float Wt[32 * 129];
    __shared__ __align__(16) float Bl[32 * 260];
    const int b  = blockIdx.z;
    const int i0 = blockIdx.y * 32;
    const int c0 = blockIdx.x * 256;
    const int t  = threadIdx.x;
    const float* sp = soft + (size_t)b * 16384;
#pragma unroll
    for (int jb = 0; jb < 4; ++jb) {
        int j  = jb * 32 + (t >> 3);
        int i4 = (t & 7) * 4;
        float4 v = *(const float4*)&sp[(size_t)j * 128 + i0 + i4];
        Wt[(i4 + 0) * 129 + j] = v.x;
        Wt[(i4 + 1) * 129 + j] = v.y;
        Wt[(i4 + 2) * 129 + j] = v.z;
        Wt[(i4 + 3) * 129 + j] = v.w;
    }
    float acc[32];
#pragma unroll
    for (int i = 0; i < 32; ++i) acc[i] = 0.f;
    const float* lv = LV + (size_t)2 * NM * 1024 + (size_t)b * 128 * 1024 + c0;
    for (int j0 = 0; j0 < 128; j0 += 32) {
        __syncthreads();
#pragma unroll
        for (int jj8 = 0; jj8 < 8; ++jj8) {
            int j  = jj8 * 4 + (t >> 6);
            int c4 = (t & 63) * 4;
            *(float4*)&Bl[j * 260 + c4] =
                *(const float4*)&lv[(size_t)(j0 + j) * 1024 + c4];
        }
        __syncthreads();
#pragma unroll
        for (int jj = 0; jj < 32; ++jj) {
            float v = Bl[jj * 260 + t];
#pragma unroll
            for (int i = 0; i < 32; ++i)
                acc[i] = fmaf(Wt[i * 129 + j0 + jj], v, acc[i]);
        }
    }
    float* mp = ML + ((size_t)b * 128 + i0) * 1024 + c0;
#pragma unroll
    for (int i = 0; i < 32; ++i) mp[(size_t)i * 1024 + t] = acc[i];
}

// ---------------------------------------------------------------------------
// launcher
// ---------------------------------------------------------------------------
extern "C" void kernel_launch(void* const* d_in, const int* in_sizes, int n_in,
                              void* d_out, int out_size, void* d_ws, size_t ws_size,
                              hipStream_t stream)
{
    const float* x  = (const float*)d_in[0];
    const float* Wq = (const float*)d_in[1];
    const float* Wk = (const float*)d_in[2];
    const float* Wv = (const float*)d_in[3];
    float* ws   = (float*)d_ws;
    float* qkv  = ws;                               // 3*NM*1024
    float* ssqp = ws + (size_t)3 * NM * 1024;       // 12288 (padded 16384)
    float* wbuf = ssqp + 16384;                     // NM*128
    float* out  = (float*)d_out;

    bimap_kernel<<<NM, 256, 0, stream>>>(x, Wq, Wk, Wv, qkv);
    eig_fn_kernel<0><<<NMAT3 / 8, 256, 0, stream>>>(qkv, qkv, ssqp, 0.0f);
    qk_weights_kernel<<<dim3(4, 4, 32), 256, 0, stream>>>(qkv, ssqp, wbuf);
    softmax_kernel<<<32, 256, 0, stream>>>(wbuf);
    meanlog_kernel<<<dim3(4, 4, 32), 256, 0, stream>>>(wbuf, qkv, qkv);
    eig_fn_kernel<1><<<NM / 8, 256, 0, stream>>>(qkv, out, nullptr, 16.0f);
}